// Round 2
// 244.018 us; speedup vs baseline: 1.1036x; 1.1036x over previous
//
#include <hip/hip_runtime.h>

// MS Deformable Attention 3D — R5: R4 (channel-vectorized gather) with the
// k_valproj epilogue chunking fixed (32 ch/head = 4 x uint4, not 8).

#define EE   256
#define HH   8
#define LL   4
#define NQq  10000
#define BSB  2
#define LENV 13294
#define MQ   16
#define ROWS_V (BSB * LENV)   // 26588

// workspace layout (bytes):
//   wcat  @ 0         : 393,216   (also front guard for v_ws underreads >= -6464B)
//   v_ws  @ 393,216   : 13,613,056
//   wval  @ 14,006,272: 131,072   (also back guard for v_ws overreads <= ~1KB)
//   wout  @ 14,137,344: 131,072
#define VWS_OFF 393216

typedef unsigned short u16;
typedef unsigned int   u32;
typedef __attribute__((ext_vector_type(8))) short bf16x8;
typedef __attribute__((ext_vector_type(4))) float f32x4;

__device__ __forceinline__ u32 bf16_of(float f) {
  u32 u = __float_as_uint(f);
  return (u + 0x7FFFu + ((u >> 16) & 1u)) >> 16;   // RNE
}
__device__ __forceinline__ float blo(u32 u) { return __uint_as_float(u << 16); }
__device__ __forceinline__ float bhi(u32 u) { return __uint_as_float(u & 0xFFFF0000u); }

__device__ __forceinline__ uint4 pack8(const float* f) {
  uint4 u;
  u.x = bf16_of(f[0]) | (bf16_of(f[1]) << 16);
  u.y = bf16_of(f[2]) | (bf16_of(f[3]) << 16);
  u.z = bf16_of(f[4]) | (bf16_of(f[5]) << 16);
  u.w = bf16_of(f[6]) | (bf16_of(f[7]) << 16);
  return u;
}

__device__ __forceinline__ void acc8(float o[8], uint4 q, float w) {
  o[0] += w * blo(q.x); o[1] += w * bhi(q.x);
  o[2] += w * blo(q.y); o[3] += w * bhi(q.y);
  o[4] += w * blo(q.z); o[5] += w * bhi(q.z);
  o[6] += w * blo(q.w); o[7] += w * bhi(q.w);
}

// ---- K0: weights -> bf16 B-fragment layout ----------------------------------
// frag element j of lane l, k-step s, n-tile t:  B[k = s*32+(l>>4)*8+j][n = t*16+(l&15)]
// stored at ((t*8+s)*64+l)*8 + j
__global__ __launch_bounds__(64) void k_prep(
    const float* __restrict__ W_off, const float* __restrict__ W_attn,
    const float* __restrict__ W_val, const float* __restrict__ W_out,
    u16* __restrict__ wcat, u16* __restrict__ wval, u16* __restrict__ wout) {
  const int tile = blockIdx.x >> 3, s = blockIdx.x & 7;
  const int l = threadIdx.x, quad = l >> 4, r16 = l & 15;
  float f[8];
  u16* dst;
  if (tile < 48) {            // concat(W_off[256x512], W_attn[256x256])
    int col = tile * 16 + r16;
#pragma unroll
    for (int j = 0; j < 8; ++j) {
      int k = s * 32 + quad * 8 + j;
      f[j] = (col < 512) ? W_off[k * 512 + col] : W_attn[k * 256 + (col - 512)];
    }
    dst = wcat + ((tile * 8 + s) * 64 + l) * 8;
  } else if (tile < 64) {     // W_val[256x256]
    int col = (tile - 48) * 16 + r16;
#pragma unroll
    for (int j = 0; j < 8; ++j) f[j] = W_val[(s * 32 + quad * 8 + j) * 256 + col];
    dst = wval + (((tile - 48) * 8 + s) * 64 + l) * 8;
  } else {                    // W_out[256x256]
    int col = (tile - 64) * 16 + r16;
#pragma unroll
    for (int j = 0; j < 8; ++j) f[j] = W_out[(s * 32 + quad * 8 + j) * 256 + col];
    dst = wout + (((tile - 64) * 8 + s) * 64 + l) * 8;
  }
  *(uint4*)dst = pack8(f);
}

// ---- K1: value projection, MFMA, 64 rows/block, bf16 output -----------------
__global__ __launch_bounds__(256) void k_valproj(
    const float* __restrict__ value, const float* __restrict__ b_val,
    const u16* __restrict__ wval, u16* __restrict__ v_ws) {
  __shared__ __align__(16) u16 sA[64][264];   // bf16 staged A; later aliased as result
  const int tid = threadIdx.x;
  const int g0 = blockIdx.x * 64;
#pragma unroll
  for (int ch = 0; ch < 8; ++ch) {
    int fidx = ch * 2048 + tid * 8;
    int row = fidx >> 8, col = fidx & 255;
    int g = g0 + row;
    float fv[8] = {0.f, 0.f, 0.f, 0.f, 0.f, 0.f, 0.f, 0.f};
    if (g < ROWS_V) {
      float4 a = *(const float4*)(value + (long)g * 256 + col);
      float4 b = *(const float4*)(value + (long)g * 256 + col + 4);
      fv[0] = a.x; fv[1] = a.y; fv[2] = a.z; fv[3] = a.w;
      fv[4] = b.x; fv[5] = b.y; fv[6] = b.z; fv[7] = b.w;
    }
    *(uint4*)&sA[row][col] = pack8(fv);
  }
  __syncthreads();
  const int wave = tid >> 6, lane = tid & 63, quad = lane >> 4, r16 = lane & 15;
  f32x4 acc[4][4] = {};
  for (int s = 0; s < 8; ++s) {
    bf16x8 af[4];
#pragma unroll
    for (int mt = 0; mt < 4; ++mt)
      af[mt] = *(const bf16x8*)&sA[mt * 16 + r16][s * 32 + quad * 8];
#pragma unroll
    for (int nt = 0; nt < 4; ++nt) {
      bf16x8 bfg = *(const bf16x8*)(wval + (((wave * 4 + nt) * 8 + s) * 64 + lane) * 8);
#pragma unroll
      for (int mt = 0; mt < 4; ++mt)
        acc[nt][mt] = __builtin_amdgcn_mfma_f32_16x16x32_bf16(af[mt], bfg, acc[nt][mt], 0, 0, 0);
    }
  }
  __syncthreads();
  // +bias, bf16, transpose-store into sA (dead) for coalesced global write
#pragma unroll
  for (int nt = 0; nt < 4; ++nt) {
    int col = (wave * 4 + nt) * 16 + r16;
    float bias = b_val[col];
#pragma unroll
    for (int mt = 0; mt < 4; ++mt)
#pragma unroll
      for (int rr = 0; rr < 4; ++rr)
        sA[mt * 16 + quad * 4 + rr][col] = (u16)bf16_of(acc[nt][mt][rr] + bias);
  }
  __syncthreads();
  // vectorized epilogue: 64 rows x 8 heads x 4 chunks of 16B = 2048 chunks;
  // each of 256 threads writes 8 chunks, strided so consecutive lanes fill
  // consecutive 16B of the same 64B head-row segment.
#pragma unroll
  for (int it = 0; it < 8; ++it) {
    int chunk = it * 256 + tid;        // 0..2047
    int r  = chunk >> 5;               // row 0..63
    int hc = chunk & 31;               // head*4 + quarter
    int h2 = hc >> 2, qq = hc & 3;
    int g = g0 + r;
    if (g < ROWS_V) {
      int bb = g / LENV, pix = g - bb * LENV;
      *(uint4*)(v_ws + ((long)((bb * 8 + h2) * LENV + pix) * 32 + qq * 8)) =
          *(const uint4*)&sA[r][h2 * 32 + qq * 8];
    }
  }
}

// ---- K2: 16 queries/block, 512 threads: GEMM1 -> softmax -> records ->
//          gather -> out-proj --------------------------------------------------
__global__ __launch_bounds__(512, 4) void k_attn(
    const float* __restrict__ query, const float* __restrict__ query_pos,
    const float* __restrict__ refpts,
    const float* __restrict__ b_off, const float* __restrict__ b_attn,
    const float* __restrict__ b_out,
    const u16* __restrict__ wcat, const u16* __restrict__ wout,
    const char* __restrict__ wsb, float* __restrict__ out) {
  __shared__ __align__(16) char smem[65536];
  u16   (*sQ)[264]  = (u16(*)[264])smem;     // staged q (bf16)
  float (*sC)[772]  = (float(*)[772])smem;   // GEMM1 C (after sQ dead)
  uint4 (*sTab)[256] = (uint4(*)[256])smem;  // records [m][swizzled s] (after sC dead)
  u16   (*sO)[264]  = (u16(*)[264])smem;     // gather output (after sTab dead)

  const int tid = threadIdx.x;
  const int g0 = blockIdx.x * MQ;
  const int b = g0 / NQq;
  const int q0 = g0 - b * NQq;
  const int wave = tid >> 6, lane = tid & 63, quad = lane >> 4, r16 = lane & 15;

  // phase 0: stage q = query + query_pos as bf16
  {
    int fidx = tid * 8;
    int row = fidx >> 8, col = fidx & 255;
    long base = ((long)(b * NQq + q0 + row)) * 256 + col;
    float4 a0 = *(const float4*)(query + base);
    float4 a1 = *(const float4*)(query + base + 4);
    float4 p0 = *(const float4*)(query_pos + base);
    float4 p1 = *(const float4*)(query_pos + base + 4);
    float fv[8] = {a0.x + p0.x, a0.y + p0.y, a0.z + p0.z, a0.w + p0.w,
                   a1.x + p1.x, a1.y + p1.y, a1.z + p1.z, a1.w + p1.w};
    *(uint4*)&sQ[row][col] = pack8(fv);
  }
  __syncthreads();

  // phase 1: C[16][768] = q @ concat(W_off, W_attn)   (48 n-tiles / 8 waves)
  f32x4 acc[6] = {};
  for (int s = 0; s < 8; ++s) {
    bf16x8 af = *(const bf16x8*)&sQ[r16][s * 32 + quad * 8];
#pragma unroll
    for (int t6 = 0; t6 < 6; ++t6) {
      int tile = wave * 6 + t6;
      bf16x8 bfg = *(const bf16x8*)(wcat + ((tile * 8 + s) * 64 + lane) * 8);
      acc[t6] = __builtin_amdgcn_mfma_f32_16x16x32_bf16(af, bfg, acc[t6], 0, 0, 0);
    }
  }
  __syncthreads();                       // sQ dead
#pragma unroll
  for (int t6 = 0; t6 < 6; ++t6) {
    int col = (wave * 6 + t6) * 16 + r16;
#pragma unroll
    for (int rr = 0; rr < 4; ++rr)
      sC[quad * 4 + rr][col] = acc[t6][rr];
  }
  __syncthreads();

  // phase 2: softmax per (m, h) over 32 logits, all 512 threads:
  // thread = (m, h, g), g owns 8 logits; 4-lane shfl reduce
  {
    const int m = tid >> 5, hh = (tid >> 2) & 7, g = tid & 3;
    float* p = &sC[m][512 + hh * 32 + g * 8];
    const float* ba = b_attn + hh * 32 + g * 8;
    float v[8];
    float mx = -1e30f;
#pragma unroll
    for (int j = 0; j < 8; ++j) { v[j] = p[j] + ba[j]; mx = fmaxf(mx, v[j]); }
    mx = fmaxf(mx, __shfl_xor(mx, 1));
    mx = fmaxf(mx, __shfl_xor(mx, 2));
    float sum = 0.f;
#pragma unroll
    for (int j = 0; j < 8; ++j) { v[j] = __expf(v[j] - mx); sum += v[j]; }
    sum += __shfl_xor(sum, 1);
    sum += __shfl_xor(sum, 2);
    float inv = 1.f / sum;
#pragma unroll
    for (int j = 0; j < 8; ++j) p[j] = v[j] * inv;
  }
  __syncthreads();

  // phase 3: build packed records (regs bridge sC -> sTab alias)
  // record: .x = (w00|w01), .y = (w10|w11) bf16 pairs;
  //         .z = signed byte offset of corner00 (x,y clamped to [-1, Wl-1]);
  //         .w = dy byte stride (clamped at bottom edge).
  // x+1 corner is an unconditional +64B; invalid corners have weight == 0 and
  // their guard reads land in the (finite) weight tables around v_ws.
  uint4 recs[8];
  {
    const int s = tid & 255, mh = tid >> 8;
    const int l = (s >> 3) & 3;
    const int WlI[4] = {100, 50, 25, 13};
    const int baseI[4] = {0, 10000, 12500, 13125};
    const int Wl = WlI[l], Hl = WlI[l], base = baseI[l];
    const float WlF = (float)Wl;
    const float box = b_off[2 * s], boy = b_off[2 * s + 1];
#pragma unroll
    for (int mm = 0; mm < 8; ++mm) {
      int m = mh * 8 + mm;
      float w = sC[m][512 + s];
      float ax = sC[m][2 * s], ay = sC[m][2 * s + 1];
      float2 rp = *(const float2*)(refpts + (((long)(b * NQq + q0 + m)) * LL + l) * 2);
      float x = rp.x * WlF + (ax + box) - 0.5f;
      float y = rp.y * WlF + (ay + boy) - 0.5f;
      float fx0 = floorf(x), fy0 = floorf(y);
      int x0 = (int)fx0, y0 = (int)fy0;
      float fx = x - fx0, fy = y - fy0;
      bool xv0 = (x0 >= 0) & (x0 < Wl);
      bool xv1 = (x0 >= -1) & (x0 < Wl - 1);
      bool yv0 = (y0 >= 0) & (y0 < Hl);
      bool yv1 = (y0 >= -1) & (y0 < Hl - 1);
      float w00 = w * (1.f - fx) * (1.f - fy) * (float)(xv0 & yv0);
      float w01 = w * fx * (1.f - fy) * (float)(xv1 & yv0);
      float w10 = w * (1.f - fx) * fy * (float)(xv0 & yv1);
      float w11 = w * fx * fy * (float)(xv1 & yv1);
      int x0a = min(max(x0, -1), Wl - 1);
      int y0a = min(max(y0, -1), Hl - 1);
      int y1c = min(max(y0 + 1, 0), Hl - 1);
      int o00 = (base + y0a * Wl + x0a) * 64;        // bytes, may be -6464 min
      u32 dyb = (u32)((y1c - y0a) * Wl) * 64u;       // bytes
      uint4 rec;
      rec.x = bf16_of(w00) | (bf16_of(w01) << 16);
      rec.y = bf16_of(w10) | (bf16_of(w11) << 16);
      rec.z = (u32)o00;
      rec.w = dyb;
      recs[mm] = rec;
    }
  }
  __syncthreads();                       // sC dead
  {
    const int s = tid & 255, mh = tid >> 8;
    const int jsw = (s & 224) | ((s + (s >> 5)) & 31);   // bank swizzle over h
#pragma unroll
    for (int mm = 0; mm < 8; ++mm) sTab[mh * 8 + mm][jsw] = recs[mm];
  }
  __syncthreads();

  // phase 4: gather — thread = (m:16, h:8, c4:4); 8 channels via dwordx4,
  // 4 lanes cover one 64B corner row (coalesced)
  {
    const int c4 = tid & 3, hh = (tid >> 2) & 7, m = tid >> 5;
    const u32 vb = (u32)VWS_OFF + (u32)(b * 8 + hh) * (u32)(LENV * 64) + (u32)c4 * 16u;
    float oacc[8] = {};
#pragma unroll 4
    for (int i = 0; i < 32; ++i) {
      const int srow = (hh << 5) | ((i + hh) & 31);
      uint4 r = sTab[m][srow];
      u32 off0 = vb + r.z;               // two's-complement add handles o00 < 0
      u32 off1 = off0 + r.w;
      uint4 q00 = *(const uint4*)(wsb + off0);
      uint4 q01 = *(const uint4*)(wsb + off0 + 64);
      uint4 q10 = *(const uint4*)(wsb + off1);
      uint4 q11 = *(const uint4*)(wsb + off1 + 64);
      float w00 = blo(r.x), w01 = bhi(r.x);
      float w10 = blo(r.y), w11 = bhi(r.y);
      acc8(oacc, q00, w00);
      acc8(oacc, q01, w01);
      acc8(oacc, q10, w10);
      acc8(oacc, q11, w11);
    }
    __syncthreads();                     // sTab dead
    *(uint4*)&sO[m][hh * 32 + c4 * 8] = pack8(oacc);
  }
  __syncthreads();

  // phase 5: out = gathered @ W_out + b_out  (16 n-tiles / 8 waves)
  f32x4 acc2[2] = {};
  for (int s = 0; s < 8; ++s) {
    bf16x8 af = *(const bf16x8*)&sO[r16][s * 32 + quad * 8];
#pragma unroll
    for (int t2 = 0; t2 < 2; ++t2) {
      int tile = wave * 2 + t2;
      bf16x8 bfg = *(const bf16x8*)(wout + ((tile * 8 + s) * 64 + lane) * 8);
      acc2[t2] = __builtin_amdgcn_mfma_f32_16x16x32_bf16(af, bfg, acc2[t2], 0, 0, 0);
    }
  }
#pragma unroll
  for (int t2 = 0; t2 < 2; ++t2) {
    int col = (wave * 2 + t2) * 16 + r16;
    float bias = b_out[col];
#pragma unroll
    for (int rr = 0; rr < 4; ++rr) {
      int row = quad * 4 + rr;
      out[((long)(b * NQq + q0 + row)) * 256 + col] = acc2[t2][rr] + bias;
    }
  }
}

extern "C" void kernel_launch(void* const* d_in, const int* in_sizes, int n_in,
                              void* d_out, int out_size, void* d_ws, size_t ws_size,
                              hipStream_t stream) {
  const float* query     = (const float*)d_in[0];
  const float* value     = (const float*)d_in[1];
  const float* query_pos = (const float*)d_in[2];
  const float* refpts    = (const float*)d_in[3];
  const float* W_off     = (const float*)d_in[5];
  const float* b_off     = (const float*)d_in[6];
  const float* W_attn    = (const float*)d_in[7];
  const float* b_attn    = (const float*)d_in[8];
  const float* W_val     = (const float*)d_in[9];
  const float* b_val     = (const float*)d_in[10];
  const float* W_out     = (const float*)d_in[11];
  const float* b_out     = (const float*)d_in[12];
  float* out = (float*)d_out;

  char* ws = (char*)d_ws;
  u16* wcat = (u16*)ws;                                   //    393,216 B @ 0
  u16* v_ws = (u16*)(ws + VWS_OFF);                       // 13,613,056 B
  u16* wval = (u16*)(ws + VWS_OFF + 13613056);            //    131,072 B
  u16* wout = (u16*)(ws + VWS_OFF + 13613056 + 131072);   //    131,072 B

  k_prep<<<dim3(80 * 8), dim3(64), 0, stream>>>(W_off, W_attn, W_val, W_out,
                                                wcat, wval, wout);
  k_valproj<<<dim3((ROWS_V + 63) / 64), dim3(256), 0, stream>>>(value, b_val, wval, v_ws);
  k_attn<<<dim3(BSB * NQq / MQ), dim3(512), 0, stream>>>(
      query, query_pos, refpts, b_off, b_attn, b_out, wcat, wout, ws, out);
}

// Round 3
// 237.251 us; speedup vs baseline: 1.1351x; 1.0285x over previous
//
#include <hip/hip_runtime.h>

// MS Deformable Attention 3D — R6: R5 + compact record tables (48 KB split
// sWgt/sOff instead of 64 KB sTab) -> LDS max 49.4 KB -> 3 blocks/CU,
// __launch_bounds__(512,6) for 24 waves/CU latency hiding.

#define EE   256
#define HH   8
#define LL   4
#define NQq  10000
#define BSB  2
#define LENV 13294
#define MQ   16
#define ROWS_V (BSB * LENV)   // 26588

// workspace layout (bytes):
//   wcat  @ 0         : 393,216   (also front guard for v_ws underreads >= -6464B)
//   v_ws  @ 393,216   : 13,613,056
//   wval  @ 14,006,272: 131,072   (also back guard for v_ws overreads <= ~6.5KB)
//   wout  @ 14,137,344: 131,072
#define VWS_OFF 393216

typedef unsigned short u16;
typedef unsigned int   u32;
typedef __attribute__((ext_vector_type(8))) short bf16x8;
typedef __attribute__((ext_vector_type(4))) float f32x4;

__device__ __forceinline__ u32 bf16_of(float f) {
  u32 u = __float_as_uint(f);
  return (u + 0x7FFFu + ((u >> 16) & 1u)) >> 16;   // RNE
}
__device__ __forceinline__ float blo(u32 u) { return __uint_as_float(u << 16); }
__device__ __forceinline__ float bhi(u32 u) { return __uint_as_float(u & 0xFFFF0000u); }

__device__ __forceinline__ uint4 pack8(const float* f) {
  uint4 u;
  u.x = bf16_of(f[0]) | (bf16_of(f[1]) << 16);
  u.y = bf16_of(f[2]) | (bf16_of(f[3]) << 16);
  u.z = bf16_of(f[4]) | (bf16_of(f[5]) << 16);
  u.w = bf16_of(f[6]) | (bf16_of(f[7]) << 16);
  return u;
}

__device__ __forceinline__ void acc8(float o[8], uint4 q, float w) {
  o[0] += w * blo(q.x); o[1] += w * bhi(q.x);
  o[2] += w * blo(q.y); o[3] += w * bhi(q.y);
  o[4] += w * blo(q.z); o[5] += w * bhi(q.z);
  o[6] += w * blo(q.w); o[7] += w * bhi(q.w);
}

// ---- K0: weights -> bf16 B-fragment layout ----------------------------------
__global__ __launch_bounds__(64) void k_prep(
    const float* __restrict__ W_off, const float* __restrict__ W_attn,
    const float* __restrict__ W_val, const float* __restrict__ W_out,
    u16* __restrict__ wcat, u16* __restrict__ wval, u16* __restrict__ wout) {
  const int tile = blockIdx.x >> 3, s = blockIdx.x & 7;
  const int l = threadIdx.x, quad = l >> 4, r16 = l & 15;
  float f[8];
  u16* dst;
  if (tile < 48) {            // concat(W_off[256x512], W_attn[256x256])
    int col = tile * 16 + r16;
#pragma unroll
    for (int j = 0; j < 8; ++j) {
      int k = s * 32 + quad * 8 + j;
      f[j] = (col < 512) ? W_off[k * 512 + col] : W_attn[k * 256 + (col - 512)];
    }
    dst = wcat + ((tile * 8 + s) * 64 + l) * 8;
  } else if (tile < 64) {     // W_val[256x256]
    int col = (tile - 48) * 16 + r16;
#pragma unroll
    for (int j = 0; j < 8; ++j) f[j] = W_val[(s * 32 + quad * 8 + j) * 256 + col];
    dst = wval + (((tile - 48) * 8 + s) * 64 + l) * 8;
  } else {                    // W_out[256x256]
    int col = (tile - 64) * 16 + r16;
#pragma unroll
    for (int j = 0; j < 8; ++j) f[j] = W_out[(s * 32 + quad * 8 + j) * 256 + col];
    dst = wout + (((tile - 64) * 8 + s) * 64 + l) * 8;
  }
  *(uint4*)dst = pack8(f);
}

// ---- K1: value projection, MFMA, 64 rows/block, bf16 output -----------------
__global__ __launch_bounds__(256) void k_valproj(
    const float* __restrict__ value, const float* __restrict__ b_val,
    const u16* __restrict__ wval, u16* __restrict__ v_ws) {
  __shared__ __align__(16) u16 sA[64][264];
  const int tid = threadIdx.x;
  const int g0 = blockIdx.x * 64;
#pragma unroll
  for (int ch = 0; ch < 8; ++ch) {
    int fidx = ch * 2048 + tid * 8;
    int row = fidx >> 8, col = fidx & 255;
    int g = g0 + row;
    float fv[8] = {0.f, 0.f, 0.f, 0.f, 0.f, 0.f, 0.f, 0.f};
    if (g < ROWS_V) {
      float4 a = *(const float4*)(value + (long)g * 256 + col);
      float4 b = *(const float4*)(value + (long)g * 256 + col + 4);
      fv[0] = a.x; fv[1] = a.y; fv[2] = a.z; fv[3] = a.w;
      fv[4] = b.x; fv[5] = b.y; fv[6] = b.z; fv[7] = b.w;
    }
    *(uint4*)&sA[row][col] = pack8(fv);
  }
  __syncthreads();
  const int wave = tid >> 6, lane = tid & 63, quad = lane >> 4, r16 = lane & 15;
  f32x4 acc[4][4] = {};
  for (int s = 0; s < 8; ++s) {
    bf16x8 af[4];
#pragma unroll
    for (int mt = 0; mt < 4; ++mt)
      af[mt] = *(const bf16x8*)&sA[mt * 16 + r16][s * 32 + quad * 8];
#pragma unroll
    for (int nt = 0; nt < 4; ++nt) {
      bf16x8 bfg = *(const bf16x8*)(wval + (((wave * 4 + nt) * 8 + s) * 64 + lane) * 8);
#pragma unroll
      for (int mt = 0; mt < 4; ++mt)
        acc[nt][mt] = __builtin_amdgcn_mfma_f32_16x16x32_bf16(af[mt], bfg, acc[nt][mt], 0, 0, 0);
    }
  }
  __syncthreads();
#pragma unroll
  for (int nt = 0; nt < 4; ++nt) {
    int col = (wave * 4 + nt) * 16 + r16;
    float bias = b_val[col];
#pragma unroll
    for (int mt = 0; mt < 4; ++mt)
#pragma unroll
      for (int rr = 0; rr < 4; ++rr)
        sA[mt * 16 + quad * 4 + rr][col] = (u16)bf16_of(acc[nt][mt][rr] + bias);
  }
  __syncthreads();
  // epilogue: 64 rows x 8 heads x 4 chunks of 16B = 2048 chunks
#pragma unroll
  for (int it = 0; it < 8; ++it) {
    int chunk = it * 256 + tid;        // 0..2047
    int r  = chunk >> 5;               // row 0..63
    int hc = chunk & 31;               // head*4 + quarter
    int h2 = hc >> 2, qq = hc & 3;
    int g = g0 + r;
    if (g < ROWS_V) {
      int bb = g / LENV, pix = g - bb * LENV;
      *(uint4*)(v_ws + ((long)((bb * 8 + h2) * LENV + pix) * 32 + qq * 8)) =
          *(const uint4*)&sA[r][h2 * 32 + qq * 8];
    }
  }
}

// ---- K2: 16 queries/block, 512 threads ---------------------------------------
__global__ __launch_bounds__(512, 6) void k_attn(
    const float* __restrict__ query, const float* __restrict__ query_pos,
    const float* __restrict__ refpts,
    const float* __restrict__ b_off, const float* __restrict__ b_attn,
    const float* __restrict__ b_out,
    const u16* __restrict__ wcat, const u16* __restrict__ wout,
    const char* __restrict__ wsb, float* __restrict__ out) {
  __shared__ __align__(16) char smem[49408];
  u16   (*sQ)[264]   = (u16(*)[264])smem;          // staged q (bf16)
  float (*sC)[772]   = (float(*)[772])smem;        // GEMM1 C (after sQ dead)
  uint2 (*sWgt)[256] = (uint2(*)[256])smem;        // record weights (after sC dead)
  u32   (*sOff)[256] = (u32(*)[256])(smem + 32768);// packed o00|dy
  u16   (*sO)[264]   = (u16(*)[264])smem;          // gather output (after tables dead)

  const int tid = threadIdx.x;
  const int g0 = blockIdx.x * MQ;
  const int b = g0 / NQq;
  const int q0 = g0 - b * NQq;
  const int wave = tid >> 6, lane = tid & 63, quad = lane >> 4, r16 = lane & 15;

  // phase 0: stage q = query + query_pos as bf16
  {
    int fidx = tid * 8;
    int row = fidx >> 8, col = fidx & 255;
    long base = ((long)(b * NQq + q0 + row)) * 256 + col;
    float4 a0 = *(const float4*)(query + base);
    float4 a1 = *(const float4*)(query + base + 4);
    float4 p0 = *(const float4*)(query_pos + base);
    float4 p1 = *(const float4*)(query_pos + base + 4);
    float fv[8] = {a0.x + p0.x, a0.y + p0.y, a0.z + p0.z, a0.w + p0.w,
                   a1.x + p1.x, a1.y + p1.y, a1.z + p1.z, a1.w + p1.w};
    *(uint4*)&sQ[row][col] = pack8(fv);
  }
  __syncthreads();

  // phase 1: C[16][768] = q @ concat(W_off, W_attn)   (48 n-tiles / 8 waves)
  f32x4 acc[6] = {};
  for (int s = 0; s < 8; ++s) {
    bf16x8 af = *(const bf16x8*)&sQ[r16][s * 32 + quad * 8];
#pragma unroll
    for (int t6 = 0; t6 < 6; ++t6) {
      int tile = wave * 6 + t6;
      bf16x8 bfg = *(const bf16x8*)(wcat + ((tile * 8 + s) * 64 + lane) * 8);
      acc[t6] = __builtin_amdgcn_mfma_f32_16x16x32_bf16(af, bfg, acc[t6], 0, 0, 0);
    }
  }
  __syncthreads();                       // sQ dead
#pragma unroll
  for (int t6 = 0; t6 < 6; ++t6) {
    int col = (wave * 6 + t6) * 16 + r16;
#pragma unroll
    for (int rr = 0; rr < 4; ++rr)
      sC[quad * 4 + rr][col] = acc[t6][rr];
  }
  __syncthreads();

  // phase 2: softmax per (m, h) over 32 logits; thread = (m, h, g), g owns 8
  {
    const int m = tid >> 5, hh = (tid >> 2) & 7, g = tid & 3;
    float* p = &sC[m][512 + hh * 32 + g * 8];
    const float* ba = b_attn + hh * 32 + g * 8;
    float v[8];
    float mx = -1e30f;
#pragma unroll
    for (int j = 0; j < 8; ++j) { v[j] = p[j] + ba[j]; mx = fmaxf(mx, v[j]); }
    mx = fmaxf(mx, __shfl_xor(mx, 1));
    mx = fmaxf(mx, __shfl_xor(mx, 2));
    float sum = 0.f;
#pragma unroll
    for (int j = 0; j < 8; ++j) { v[j] = __expf(v[j] - mx); sum += v[j]; }
    sum += __shfl_xor(sum, 1);
    sum += __shfl_xor(sum, 2);
    float inv = 1.f / sum;
#pragma unroll
    for (int j = 0; j < 8; ++j) p[j] = v[j] * inv;
  }
  __syncthreads();

  // phase 3: build packed records.
  //   wgt = (w00|w01, w10|w11) bf16 pairs
  //   off = (o00/64 + 128) in bits 0..13  |  (dy/64) << 14   (dy/64 <= 100)
  // o00 byte offset of corner00, x/y clamped to [-1, Wl-1]; x+1 corner = +64B.
  // Invalid corners have weight 0; guard reads land in wcat/wval around v_ws.
  uint2 wrecs[8];
  u32   orecs[8];
  {
    const int s = tid & 255, mh = tid >> 8;
    const int l = (s >> 3) & 3;
    const int WlI[4] = {100, 50, 25, 13};
    const int baseI[4] = {0, 10000, 12500, 13125};
    const int Wl = WlI[l], Hl = WlI[l], base = baseI[l];
    const float WlF = (float)Wl;
    const float box = b_off[2 * s], boy = b_off[2 * s + 1];
#pragma unroll
    for (int mm = 0; mm < 8; ++mm) {
      int m = mh * 8 + mm;
      float w = sC[m][512 + s];
      float ax = sC[m][2 * s], ay = sC[m][2 * s + 1];
      float2 rp = *(const float2*)(refpts + (((long)(b * NQq + q0 + m)) * LL + l) * 2);
      float x = rp.x * WlF + (ax + box) - 0.5f;
      float y = rp.y * WlF + (ay + boy) - 0.5f;
      float fx0 = floorf(x), fy0 = floorf(y);
      int x0 = (int)fx0, y0 = (int)fy0;
      float fx = x - fx0, fy = y - fy0;
      bool xv0 = (x0 >= 0) & (x0 < Wl);
      bool xv1 = (x0 >= -1) & (x0 < Wl - 1);
      bool yv0 = (y0 >= 0) & (y0 < Hl);
      bool yv1 = (y0 >= -1) & (y0 < Hl - 1);
      float w00 = w * (1.f - fx) * (1.f - fy) * (float)(xv0 & yv0);
      float w01 = w * fx * (1.f - fy) * (float)(xv1 & yv0);
      float w10 = w * (1.f - fx) * fy * (float)(xv0 & yv1);
      float w11 = w * fx * fy * (float)(xv1 & yv1);
      int x0a = min(max(x0, -1), Wl - 1);
      int y0a = min(max(y0, -1), Hl - 1);
      int y1c = min(max(y0 + 1, 0), Hl - 1);
      int o00u = base + y0a * Wl + x0a;              // units of 64B, in [-101, 13293]
      u32 dyu  = (u32)((y1c - y0a) * Wl);            // units of 64B, 0..100
      wrecs[mm].x = bf16_of(w00) | (bf16_of(w01) << 16);
      wrecs[mm].y = bf16_of(w10) | (bf16_of(w11) << 16);
      orecs[mm]   = (u32)(o00u + 128) | (dyu << 14);
    }
  }
  __syncthreads();                       // sC dead
  {
    const int s = tid & 255, mh = tid >> 8;
    const int jsw = (s & 224) | ((s + (s >> 5)) & 31);   // bank swizzle over h
#pragma unroll
    for (int mm = 0; mm < 8; ++mm) {
      sWgt[mh * 8 + mm][jsw] = wrecs[mm];
      sOff[mh * 8 + mm][jsw] = orecs[mm];
    }
  }
  __syncthreads();

  // phase 4: gather — thread = (m:16, h:8, c4:4); 8 channels via dwordx4,
  // 4 lanes cover one 64B corner row (coalesced)
  {
    const int c4 = tid & 3, hh = (tid >> 2) & 7, m = tid >> 5;
    const u32 vbm = (u32)VWS_OFF + (u32)(b * 8 + hh) * (u32)(LENV * 64)
                  + (u32)c4 * 16u - 8192u;           // folds the +128 bias
    float oacc[8] = {};
#pragma unroll 4
    for (int i = 0; i < 32; ++i) {
      const int srow = (hh << 5) | ((i + hh) & 31);
      uint2 wr = sWgt[m][srow];
      u32   po = sOff[m][srow];
      u32 off0 = vbm + ((po & 0x3FFFu) << 6);
      u32 off1 = off0 + ((po >> 14) << 6);
      uint4 q00 = *(const uint4*)(wsb + off0);
      uint4 q01 = *(const uint4*)(wsb + off0 + 64);
      uint4 q10 = *(const uint4*)(wsb + off1);
      uint4 q11 = *(const uint4*)(wsb + off1 + 64);
      float w00 = blo(wr.x), w01 = bhi(wr.x);
      float w10 = blo(wr.y), w11 = bhi(wr.y);
      acc8(oacc, q00, w00);
      acc8(oacc, q01, w01);
      acc8(oacc, q10, w10);
      acc8(oacc, q11, w11);
    }
    __syncthreads();                     // tables dead
    *(uint4*)&sO[m][hh * 32 + c4 * 8] = pack8(oacc);
  }
  __syncthreads();

  // phase 5: out = gathered @ W_out + b_out  (16 n-tiles / 8 waves)
  f32x4 acc2[2] = {};
  for (int s = 0; s < 8; ++s) {
    bf16x8 af = *(const bf16x8*)&sO[r16][s * 32 + quad * 8];
#pragma unroll
    for (int t2 = 0; t2 < 2; ++t2) {
      int tile = wave * 2 + t2;
      bf16x8 bfg = *(const bf16x8*)(wout + ((tile * 8 + s) * 64 + lane) * 8);
      acc2[t2] = __builtin_amdgcn_mfma_f32_16x16x32_bf16(af, bfg, acc2[t2], 0, 0, 0);
    }
  }
#pragma unroll
  for (int t2 = 0; t2 < 2; ++t2) {
    int col = (wave * 2 + t2) * 16 + r16;
    float bias = b_out[col];
#pragma unroll
    for (int rr = 0; rr < 4; ++rr) {
      int row = quad * 4 + rr;
      out[((long)(b * NQq + q0 + row)) * 256 + col] = acc2[t2][rr] + bias;
    }
  }
}

extern "C" void kernel_launch(void* const* d_in, const int* in_sizes, int n_in,
                              void* d_out, int out_size, void* d_ws, size_t ws_size,
                              hipStream_t stream) {
  const float* query     = (const float*)d_in[0];
  const float* value     = (const float*)d_in[1];
  const float* query_pos = (const float*)d_in[2];
  const float* refpts    = (const float*)d_in[3];
  const float* W_off     = (const float*)d_in[5];
  const float* b_off     = (const float*)d_in[6];
  const float* W_attn    = (const float*)d_in[7];
  const float* b_attn    = (const float*)d_in[8];
  const float* W_val     = (const float*)d_in[9];
  const float* b_val     = (const float*)d_in[10];
  const float* W_out     = (const float*)d_in[11];
  const float* b_out     = (const float*)d_in[12];
  float* out = (float*)d_out;

  char* ws = (char*)d_ws;
  u16* wcat = (u16*)ws;                                   //    393,216 B @ 0
  u16* v_ws = (u16*)(ws + VWS_OFF);                       // 13,613,056 B
  u16* wval = (u16*)(ws + VWS_OFF + 13613056);            //    131,072 B
  u16* wout = (u16*)(ws + VWS_OFF + 13613056 + 131072);   //    131,072 B

  k_prep<<<dim3(80 * 8), dim3(64), 0, stream>>>(W_off, W_attn, W_val, W_out,
                                                wcat, wval, wout);
  k_valproj<<<dim3((ROWS_V + 63) / 64), dim3(256), 0, stream>>>(value, b_val, wval, v_ws);
  k_attn<<<dim3(BSB * NQq / MQ), dim3(512), 0, stream>>>(
      query, query_pos, refpts, b_off, b_attn, b_out, wcat, wout, ws, out);
}

// Round 4
// 236.769 us; speedup vs baseline: 1.1374x; 1.0020x over previous
//
#include <hip/hip_runtime.h>

// MS Deformable Attention 3D — R7: R6 + (a) softmax fused into record build via
// 32-lane shuffle reductions (one fewer barrier + sC pass), (b) gather unroll
// 4->8 for 2x outstanding loads, (c) k_valproj widened to 512 threads/8 waves.

#define EE   256
#define HH   8
#define LL   4
#define NQq  10000
#define BSB  2
#define LENV 13294
#define MQ   16
#define ROWS_V (BSB * LENV)   // 26588

// workspace layout (bytes):
//   wcat  @ 0         : 393,216   (also front guard for v_ws underreads >= -6464B)
//   v_ws  @ 393,216   : 13,613,056
//   wval  @ 14,006,272: 131,072   (also back guard for v_ws overreads <= ~6.5KB)
//   wout  @ 14,137,344: 131,072
#define VWS_OFF 393216

typedef unsigned short u16;
typedef unsigned int   u32;
typedef __attribute__((ext_vector_type(8))) short bf16x8;
typedef __attribute__((ext_vector_type(4))) float f32x4;

__device__ __forceinline__ u32 bf16_of(float f) {
  u32 u = __float_as_uint(f);
  return (u + 0x7FFFu + ((u >> 16) & 1u)) >> 16;   // RNE
}
__device__ __forceinline__ float blo(u32 u) { return __uint_as_float(u << 16); }
__device__ __forceinline__ float bhi(u32 u) { return __uint_as_float(u & 0xFFFF0000u); }

__device__ __forceinline__ uint4 pack8(const float* f) {
  uint4 u;
  u.x = bf16_of(f[0]) | (bf16_of(f[1]) << 16);
  u.y = bf16_of(f[2]) | (bf16_of(f[3]) << 16);
  u.z = bf16_of(f[4]) | (bf16_of(f[5]) << 16);
  u.w = bf16_of(f[6]) | (bf16_of(f[7]) << 16);
  return u;
}

__device__ __forceinline__ void acc8(float o[8], uint4 q, float w) {
  o[0] += w * blo(q.x); o[1] += w * bhi(q.x);
  o[2] += w * blo(q.y); o[3] += w * bhi(q.y);
  o[4] += w * blo(q.z); o[5] += w * bhi(q.z);
  o[6] += w * blo(q.w); o[7] += w * bhi(q.w);
}

// ---- K0: weights -> bf16 B-fragment layout ----------------------------------
__global__ __launch_bounds__(64) void k_prep(
    const float* __restrict__ W_off, const float* __restrict__ W_attn,
    const float* __restrict__ W_val, const float* __restrict__ W_out,
    u16* __restrict__ wcat, u16* __restrict__ wval, u16* __restrict__ wout) {
  const int tile = blockIdx.x >> 3, s = blockIdx.x & 7;
  const int l = threadIdx.x, quad = l >> 4, r16 = l & 15;
  float f[8];
  u16* dst;
  if (tile < 48) {            // concat(W_off[256x512], W_attn[256x256])
    int col = tile * 16 + r16;
#pragma unroll
    for (int j = 0; j < 8; ++j) {
      int k = s * 32 + quad * 8 + j;
      f[j] = (col < 512) ? W_off[k * 512 + col] : W_attn[k * 256 + (col - 512)];
    }
    dst = wcat + ((tile * 8 + s) * 64 + l) * 8;
  } else if (tile < 64) {     // W_val[256x256]
    int col = (tile - 48) * 16 + r16;
#pragma unroll
    for (int j = 0; j < 8; ++j) f[j] = W_val[(s * 32 + quad * 8 + j) * 256 + col];
    dst = wval + (((tile - 48) * 8 + s) * 64 + l) * 8;
  } else {                    // W_out[256x256]
    int col = (tile - 64) * 16 + r16;
#pragma unroll
    for (int j = 0; j < 8; ++j) f[j] = W_out[(s * 32 + quad * 8 + j) * 256 + col];
    dst = wout + (((tile - 64) * 8 + s) * 64 + l) * 8;
  }
  *(uint4*)dst = pack8(f);
}

// ---- K1: value projection, MFMA, 64 rows/block, 512 threads / 8 waves -------
__global__ __launch_bounds__(512) void k_valproj(
    const float* __restrict__ value, const float* __restrict__ b_val,
    const u16* __restrict__ wval, u16* __restrict__ v_ws) {
  __shared__ __align__(16) u16 sA[64][264];
  const int tid = threadIdx.x;
  const int g0 = blockIdx.x * 64;
#pragma unroll
  for (int ch = 0; ch < 4; ++ch) {
    int fidx = ch * 4096 + tid * 8;
    int row = fidx >> 8, col = fidx & 255;
    int g = g0 + row;
    float fv[8] = {0.f, 0.f, 0.f, 0.f, 0.f, 0.f, 0.f, 0.f};
    if (g < ROWS_V) {
      float4 a = *(const float4*)(value + (long)g * 256 + col);
      float4 b = *(const float4*)(value + (long)g * 256 + col + 4);
      fv[0] = a.x; fv[1] = a.y; fv[2] = a.z; fv[3] = a.w;
      fv[4] = b.x; fv[5] = b.y; fv[6] = b.z; fv[7] = b.w;
    }
    *(uint4*)&sA[row][col] = pack8(fv);
  }
  __syncthreads();
  const int wave = tid >> 6, lane = tid & 63, quad = lane >> 4, r16 = lane & 15;
  f32x4 acc[2][4] = {};
  for (int s = 0; s < 8; ++s) {
    bf16x8 af[4];
#pragma unroll
    for (int mt = 0; mt < 4; ++mt)
      af[mt] = *(const bf16x8*)&sA[mt * 16 + r16][s * 32 + quad * 8];
#pragma unroll
    for (int nt = 0; nt < 2; ++nt) {
      int ntg = wave * 2 + nt;
      bf16x8 bfg = *(const bf16x8*)(wval + ((ntg * 8 + s) * 64 + lane) * 8);
#pragma unroll
      for (int mt = 0; mt < 4; ++mt)
        acc[nt][mt] = __builtin_amdgcn_mfma_f32_16x16x32_bf16(af[mt], bfg, acc[nt][mt], 0, 0, 0);
    }
  }
  __syncthreads();
#pragma unroll
  for (int nt = 0; nt < 2; ++nt) {
    int col = (wave * 2 + nt) * 16 + r16;
    float bias = b_val[col];
#pragma unroll
    for (int mt = 0; mt < 4; ++mt)
#pragma unroll
      for (int rr = 0; rr < 4; ++rr)
        sA[mt * 16 + quad * 4 + rr][col] = (u16)bf16_of(acc[nt][mt][rr] + bias);
  }
  __syncthreads();
  // epilogue: 64 rows x 8 heads x 4 chunks of 16B = 2048 chunks / 512 threads
#pragma unroll
  for (int it = 0; it < 4; ++it) {
    int chunk = it * 512 + tid;        // 0..2047
    int r  = chunk >> 5;               // row 0..63
    int hc = chunk & 31;               // head*4 + quarter
    int h2 = hc >> 2, qq = hc & 3;
    int g = g0 + r;
    if (g < ROWS_V) {
      int bb = g / LENV, pix = g - bb * LENV;
      *(uint4*)(v_ws + ((long)((bb * 8 + h2) * LENV + pix) * 32 + qq * 8)) =
          *(const uint4*)&sA[r][h2 * 32 + qq * 8];
    }
  }
}

// ---- K2: 16 queries/block, 512 threads ---------------------------------------
__global__ __launch_bounds__(512, 6) void k_attn(
    const float* __restrict__ query, const float* __restrict__ query_pos,
    const float* __restrict__ refpts,
    const float* __restrict__ b_off, const float* __restrict__ b_attn,
    const float* __restrict__ b_out,
    const u16* __restrict__ wcat, const u16* __restrict__ wout,
    const char* __restrict__ wsb, float* __restrict__ out) {
  __shared__ __align__(16) char smem[49408];
  u16   (*sQ)[264]   = (u16(*)[264])smem;          // staged q (bf16)
  float (*sC)[772]   = (float(*)[772])smem;        // GEMM1 C (after sQ dead)
  uint2 (*sWgt)[256] = (uint2(*)[256])smem;        // record weights (after sC dead)
  u32   (*sOff)[256] = (u32(*)[256])(smem + 32768);// packed o00|dy
  u16   (*sO)[264]   = (u16(*)[264])smem;          // gather output (after tables dead)

  const int tid = threadIdx.x;
  const int g0 = blockIdx.x * MQ;
  const int b = g0 / NQq;
  const int q0 = g0 - b * NQq;
  const int wave = tid >> 6, lane = tid & 63, quad = lane >> 4, r16 = lane & 15;

  // phase 0: stage q = query + query_pos as bf16
  {
    int fidx = tid * 8;
    int row = fidx >> 8, col = fidx & 255;
    long base = ((long)(b * NQq + q0 + row)) * 256 + col;
    float4 a0 = *(const float4*)(query + base);
    float4 a1 = *(const float4*)(query + base + 4);
    float4 p0 = *(const float4*)(query_pos + base);
    float4 p1 = *(const float4*)(query_pos + base + 4);
    float fv[8] = {a0.x + p0.x, a0.y + p0.y, a0.z + p0.z, a0.w + p0.w,
                   a1.x + p1.x, a1.y + p1.y, a1.z + p1.z, a1.w + p1.w};
    *(uint4*)&sQ[row][col] = pack8(fv);
  }
  __syncthreads();

  // phase 1: C[16][768] = q @ concat(W_off, W_attn)   (48 n-tiles / 8 waves)
  f32x4 acc[6] = {};
  for (int s = 0; s < 8; ++s) {
    bf16x8 af = *(const bf16x8*)&sQ[r16][s * 32 + quad * 8];
#pragma unroll
    for (int t6 = 0; t6 < 6; ++t6) {
      int tile = wave * 6 + t6;
      bf16x8 bfg = *(const bf16x8*)(wcat + ((tile * 8 + s) * 64 + lane) * 8);
      acc[t6] = __builtin_amdgcn_mfma_f32_16x16x32_bf16(af, bfg, acc[t6], 0, 0, 0);
    }
  }
  __syncthreads();                       // sQ dead
#pragma unroll
  for (int t6 = 0; t6 < 6; ++t6) {
    int col = (wave * 6 + t6) * 16 + r16;
#pragma unroll
    for (int rr = 0; rr < 4; ++rr)
      sC[quad * 4 + rr][col] = acc[t6][rr];
  }
  __syncthreads();

  // phase 2+3 fused: softmax (32-lane shuffle reduce) + record build.
  // thread = (s: 0..255, mh: 0..1). The 32 logits of (m, h) live in 32
  // consecutive 32-aligned lanes of this wave -> shfl_xor 1,2,4,8,16.
  //   wgt = (w00|w01, w10|w11) bf16 pairs
  //   off = (o00/64 + 128) in bits 0..13  |  (dy/64) << 14   (dy/64 <= 100)
  // o00 byte offset of corner00, x/y clamped to [-1, Wl-1]; x+1 corner = +64B.
  // Invalid corners have weight 0; guard reads land in wcat/wval around v_ws.
  uint2 wrecs[8];
  u32   orecs[8];
  {
    const int s = tid & 255, mh = tid >> 8;
    const int l = (s >> 3) & 3;
    const int WlI[4] = {100, 50, 25, 13};
    const int baseI[4] = {0, 10000, 12500, 13125};
    const int Wl = WlI[l], Hl = WlI[l], base = baseI[l];
    const float WlF = (float)Wl;
    const float ba  = b_attn[s];
    const float box = b_off[2 * s], boy = b_off[2 * s + 1];
#pragma unroll
    for (int mm = 0; mm < 8; ++mm) {
      int m = mh * 8 + mm;
      float logit = sC[m][512 + s] + ba;
      float mx = logit;
      mx = fmaxf(mx, __shfl_xor(mx, 1));
      mx = fmaxf(mx, __shfl_xor(mx, 2));
      mx = fmaxf(mx, __shfl_xor(mx, 4));
      mx = fmaxf(mx, __shfl_xor(mx, 8));
      mx = fmaxf(mx, __shfl_xor(mx, 16));
      float e = __expf(logit - mx);
      float sum = e;
      sum += __shfl_xor(sum, 1);
      sum += __shfl_xor(sum, 2);
      sum += __shfl_xor(sum, 4);
      sum += __shfl_xor(sum, 8);
      sum += __shfl_xor(sum, 16);
      float w = e * __frcp_rn(sum);
      float ax = sC[m][2 * s], ay = sC[m][2 * s + 1];
      float2 rp = *(const float2*)(refpts + (((long)(b * NQq + q0 + m)) * LL + l) * 2);
      float x = rp.x * WlF + (ax + box) - 0.5f;
      float y = rp.y * WlF + (ay + boy) - 0.5f;
      float fx0 = floorf(x), fy0 = floorf(y);
      int x0 = (int)fx0, y0 = (int)fy0;
      float fx = x - fx0, fy = y - fy0;
      bool xv0 = (x0 >= 0) & (x0 < Wl);
      bool xv1 = (x0 >= -1) & (x0 < Wl - 1);
      bool yv0 = (y0 >= 0) & (y0 < Hl);
      bool yv1 = (y0 >= -1) & (y0 < Hl - 1);
      float w00 = w * (1.f - fx) * (1.f - fy) * (float)(xv0 & yv0);
      float w01 = w * fx * (1.f - fy) * (float)(xv1 & yv0);
      float w10 = w * (1.f - fx) * fy * (float)(xv0 & yv1);
      float w11 = w * fx * fy * (float)(xv1 & yv1);
      int x0a = min(max(x0, -1), Wl - 1);
      int y0a = min(max(y0, -1), Hl - 1);
      int y1c = min(max(y0 + 1, 0), Hl - 1);
      int o00u = base + y0a * Wl + x0a;              // units of 64B, in [-101, 13293]
      u32 dyu  = (u32)((y1c - y0a) * Wl);            // units of 64B, 0..100
      wrecs[mm].x = bf16_of(w00) | (bf16_of(w01) << 16);
      wrecs[mm].y = bf16_of(w10) | (bf16_of(w11) << 16);
      orecs[mm]   = (u32)(o00u + 128) | (dyu << 14);
    }
  }
  __syncthreads();                       // sC dead
  {
    const int s = tid & 255, mh = tid >> 8;
    const int jsw = (s & 224) | ((s + (s >> 5)) & 31);   // bank swizzle over h
#pragma unroll
    for (int mm = 0; mm < 8; ++mm) {
      sWgt[mh * 8 + mm][jsw] = wrecs[mm];
      sOff[mh * 8 + mm][jsw] = orecs[mm];
    }
  }
  __syncthreads();

  // phase 4: gather — thread = (m:16, h:8, c4:4); 8 channels via dwordx4,
  // 4 lanes cover one 64B corner row (coalesced); unroll 8 -> 32 loads in flight
  {
    const int c4 = tid & 3, hh = (tid >> 2) & 7, m = tid >> 5;
    const u32 vbm = (u32)VWS_OFF + (u32)(b * 8 + hh) * (u32)(LENV * 64)
                  + (u32)c4 * 16u - 8192u;           // folds the +128 bias
    float oacc[8] = {};
#pragma unroll 8
    for (int i = 0; i < 32; ++i) {
      const int srow = (hh << 5) | ((i + hh) & 31);
      uint2 wr = sWgt[m][srow];
      u32   po = sOff[m][srow];
      u32 off0 = vbm + ((po & 0x3FFFu) << 6);
      u32 off1 = off0 + ((po >> 14) << 6);
      uint4 q00 = *(const uint4*)(wsb + off0);
      uint4 q01 = *(const uint4*)(wsb + off0 + 64);
      uint4 q10 = *(const uint4*)(wsb + off1);
      uint4 q11 = *(const uint4*)(wsb + off1 + 64);
      float w00 = blo(wr.x), w01 = bhi(wr.x);
      float w10 = blo(wr.y), w11 = bhi(wr.y);
      acc8(oacc, q00, w00);
      acc8(oacc, q01, w01);
      acc8(oacc, q10, w10);
      acc8(oacc, q11, w11);
    }
    __syncthreads();                     // tables dead
    *(uint4*)&sO[m][hh * 32 + c4 * 8] = pack8(oacc);
  }
  __syncthreads();

  // phase 5: out = gathered @ W_out + b_out  (16 n-tiles / 8 waves)
  f32x4 acc2[2] = {};
  for (int s = 0; s < 8; ++s) {
    bf16x8 af = *(const bf16x8*)&sO[r16][s * 32 + quad * 8];
#pragma unroll
    for (int t2 = 0; t2 < 2; ++t2) {
      int tile = wave * 2 + t2;
      bf16x8 bfg = *(const bf16x8*)(wout + ((tile * 8 + s) * 64 + lane) * 8);
      acc2[t2] = __builtin_amdgcn_mfma_f32_16x16x32_bf16(af, bfg, acc2[t2], 0, 0, 0);
    }
  }
#pragma unroll
  for (int t2 = 0; t2 < 2; ++t2) {
    int col = (wave * 2 + t2) * 16 + r16;
    float bias = b_out[col];
#pragma unroll
    for (int rr = 0; rr < 4; ++rr) {
      int row = quad * 4 + rr;
      out[((long)(b * NQq + q0 + row)) * 256 + col] = acc2[t2][rr] + bias;
    }
  }
}

extern "C" void kernel_launch(void* const* d_in, const int* in_sizes, int n_in,
                              void* d_out, int out_size, void* d_ws, size_t ws_size,
                              hipStream_t stream) {
  const float* query     = (const float*)d_in[0];
  const float* value     = (const float*)d_in[1];
  const float* query_pos = (const float*)d_in[2];
  const float* refpts    = (const float*)d_in[3];
  const float* W_off     = (const float*)d_in[5];
  const float* b_off     = (const float*)d_in[6];
  const float* W_attn    = (const float*)d_in[7];
  const float* b_attn    = (const float*)d_in[8];
  const float* W_val     = (const float*)d_in[9];
  const float* b_val     = (const float*)d_in[10];
  const float* W_out     = (const float*)d_in[11];
  const float* b_out     = (const float*)d_in[12];
  float* out = (float*)d_out;

  char* ws = (char*)d_ws;
  u16* wcat = (u16*)ws;                                   //    393,216 B @ 0
  u16* v_ws = (u16*)(ws + VWS_OFF);                       // 13,613,056 B
  u16* wval = (u16*)(ws + VWS_OFF + 13613056);            //    131,072 B
  u16* wout = (u16*)(ws + VWS_OFF + 13613056 + 131072);   //    131,072 B

  k_prep<<<dim3(80 * 8), dim3(64), 0, stream>>>(W_off, W_attn, W_val, W_out,
                                                wcat, wval, wout);
  k_valproj<<<dim3((ROWS_V + 63) / 64), dim3(512), 0, stream>>>(value, b_val, wval, v_ws);
  k_attn<<<dim3(BSB * NQq / MQ), dim3(512), 0, stream>>>(
      query, query_pos, refpts, b_off, b_attn, b_out, wcat, wout, ws, out);
}

// Round 5
// 236.573 us; speedup vs baseline: 1.1383x; 1.0008x over previous
//
#include <hip/hip_runtime.h>

// MS Deformable Attention 3D — R8: R6's k_attn (separate softmax phase, 123us)
// + manual batch-2 gather (8 loads issued before consumption, enforced by
// sched_barrier(0)) to force MLP on the L3 path; R7's 512-thread k_valproj.

#define EE   256
#define HH   8
#define LL   4
#define NQq  10000
#define BSB  2
#define LENV 13294
#define MQ   16
#define ROWS_V (BSB * LENV)   // 26588

// workspace layout (bytes):
//   wcat  @ 0         : 393,216   (also front guard for v_ws underreads >= -6464B)
//   v_ws  @ 393,216   : 13,613,056
//   wval  @ 14,006,272: 131,072   (also back guard for v_ws overreads <= ~6.5KB)
//   wout  @ 14,137,344: 131,072
#define VWS_OFF 393216

typedef unsigned short u16;
typedef unsigned int   u32;
typedef __attribute__((ext_vector_type(8))) short bf16x8;
typedef __attribute__((ext_vector_type(4))) float f32x4;

__device__ __forceinline__ u32 bf16_of(float f) {
  u32 u = __float_as_uint(f);
  return (u + 0x7FFFu + ((u >> 16) & 1u)) >> 16;   // RNE
}
__device__ __forceinline__ float blo(u32 u) { return __uint_as_float(u << 16); }
__device__ __forceinline__ float bhi(u32 u) { return __uint_as_float(u & 0xFFFF0000u); }

__device__ __forceinline__ uint4 pack8(const float* f) {
  uint4 u;
  u.x = bf16_of(f[0]) | (bf16_of(f[1]) << 16);
  u.y = bf16_of(f[2]) | (bf16_of(f[3]) << 16);
  u.z = bf16_of(f[4]) | (bf16_of(f[5]) << 16);
  u.w = bf16_of(f[6]) | (bf16_of(f[7]) << 16);
  return u;
}

__device__ __forceinline__ void acc8(float o[8], uint4 q, float w) {
  o[0] += w * blo(q.x); o[1] += w * bhi(q.x);
  o[2] += w * blo(q.y); o[3] += w * bhi(q.y);
  o[4] += w * blo(q.z); o[5] += w * bhi(q.z);
  o[6] += w * blo(q.w); o[7] += w * bhi(q.w);
}

// ---- K0: weights -> bf16 B-fragment layout ----------------------------------
__global__ __launch_bounds__(64) void k_prep(
    const float* __restrict__ W_off, const float* __restrict__ W_attn,
    const float* __restrict__ W_val, const float* __restrict__ W_out,
    u16* __restrict__ wcat, u16* __restrict__ wval, u16* __restrict__ wout) {
  const int tile = blockIdx.x >> 3, s = blockIdx.x & 7;
  const int l = threadIdx.x, quad = l >> 4, r16 = l & 15;
  float f[8];
  u16* dst;
  if (tile < 48) {            // concat(W_off[256x512], W_attn[256x256])
    int col = tile * 16 + r16;
#pragma unroll
    for (int j = 0; j < 8; ++j) {
      int k = s * 32 + quad * 8 + j;
      f[j] = (col < 512) ? W_off[k * 512 + col] : W_attn[k * 256 + (col - 512)];
    }
    dst = wcat + ((tile * 8 + s) * 64 + l) * 8;
  } else if (tile < 64) {     // W_val[256x256]
    int col = (tile - 48) * 16 + r16;
#pragma unroll
    for (int j = 0; j < 8; ++j) f[j] = W_val[(s * 32 + quad * 8 + j) * 256 + col];
    dst = wval + (((tile - 48) * 8 + s) * 64 + l) * 8;
  } else {                    // W_out[256x256]
    int col = (tile - 64) * 16 + r16;
#pragma unroll
    for (int j = 0; j < 8; ++j) f[j] = W_out[(s * 32 + quad * 8 + j) * 256 + col];
    dst = wout + (((tile - 64) * 8 + s) * 64 + l) * 8;
  }
  *(uint4*)dst = pack8(f);
}

// ---- K1: value projection, MFMA, 64 rows/block, 512 threads / 8 waves -------
__global__ __launch_bounds__(512) void k_valproj(
    const float* __restrict__ value, const float* __restrict__ b_val,
    const u16* __restrict__ wval, u16* __restrict__ v_ws) {
  __shared__ __align__(16) u16 sA[64][264];
  const int tid = threadIdx.x;
  const int g0 = blockIdx.x * 64;
#pragma unroll
  for (int ch = 0; ch < 4; ++ch) {
    int fidx = ch * 4096 + tid * 8;
    int row = fidx >> 8, col = fidx & 255;
    int g = g0 + row;
    float fv[8] = {0.f, 0.f, 0.f, 0.f, 0.f, 0.f, 0.f, 0.f};
    if (g < ROWS_V) {
      float4 a = *(const float4*)(value + (long)g * 256 + col);
      float4 b = *(const float4*)(value + (long)g * 256 + col + 4);
      fv[0] = a.x; fv[1] = a.y; fv[2] = a.z; fv[3] = a.w;
      fv[4] = b.x; fv[5] = b.y; fv[6] = b.z; fv[7] = b.w;
    }
    *(uint4*)&sA[row][col] = pack8(fv);
  }
  __syncthreads();
  const int wave = tid >> 6, lane = tid & 63, quad = lane >> 4, r16 = lane & 15;
  f32x4 acc[2][4] = {};
  for (int s = 0; s < 8; ++s) {
    bf16x8 af[4];
#pragma unroll
    for (int mt = 0; mt < 4; ++mt)
      af[mt] = *(const bf16x8*)&sA[mt * 16 + r16][s * 32 + quad * 8];
#pragma unroll
    for (int nt = 0; nt < 2; ++nt) {
      int ntg = wave * 2 + nt;
      bf16x8 bfg = *(const bf16x8*)(wval + ((ntg * 8 + s) * 64 + lane) * 8);
#pragma unroll
      for (int mt = 0; mt < 4; ++mt)
        acc[nt][mt] = __builtin_amdgcn_mfma_f32_16x16x32_bf16(af[mt], bfg, acc[nt][mt], 0, 0, 0);
    }
  }
  __syncthreads();
#pragma unroll
  for (int nt = 0; nt < 2; ++nt) {
    int col = (wave * 2 + nt) * 16 + r16;
    float bias = b_val[col];
#pragma unroll
    for (int mt = 0; mt < 4; ++mt)
#pragma unroll
      for (int rr = 0; rr < 4; ++rr)
        sA[mt * 16 + quad * 4 + rr][col] = (u16)bf16_of(acc[nt][mt][rr] + bias);
  }
  __syncthreads();
  // epilogue: 64 rows x 8 heads x 4 chunks of 16B = 2048 chunks / 512 threads
#pragma unroll
  for (int it = 0; it < 4; ++it) {
    int chunk = it * 512 + tid;        // 0..2047
    int r  = chunk >> 5;               // row 0..63
    int hc = chunk & 31;               // head*4 + quarter
    int h2 = hc >> 2, qq = hc & 3;
    int g = g0 + r;
    if (g < ROWS_V) {
      int bb = g / LENV, pix = g - bb * LENV;
      *(uint4*)(v_ws + ((long)((bb * 8 + h2) * LENV + pix) * 32 + qq * 8)) =
          *(const uint4*)&sA[r][h2 * 32 + qq * 8];
    }
  }
}

// ---- K2: 16 queries/block, 512 threads ---------------------------------------
__global__ __launch_bounds__(512, 6) void k_attn(
    const float* __restrict__ query, const float* __restrict__ query_pos,
    const float* __restrict__ refpts,
    const float* __restrict__ b_off, const float* __restrict__ b_attn,
    const float* __restrict__ b_out,
    const u16* __restrict__ wcat, const u16* __restrict__ wout,
    const char* __restrict__ wsb, float* __restrict__ out) {
  __shared__ __align__(16) char smem[49408];
  u16   (*sQ)[264]   = (u16(*)[264])smem;          // staged q (bf16)
  float (*sC)[772]   = (float(*)[772])smem;        // GEMM1 C (after sQ dead)
  uint2 (*sWgt)[256] = (uint2(*)[256])smem;        // record weights (after sC dead)
  u32   (*sOff)[256] = (u32(*)[256])(smem + 32768);// packed o00|dy
  u16   (*sO)[264]   = (u16(*)[264])smem;          // gather output (after tables dead)

  const int tid = threadIdx.x;
  const int g0 = blockIdx.x * MQ;
  const int b = g0 / NQq;
  const int q0 = g0 - b * NQq;
  const int wave = tid >> 6, lane = tid & 63, quad = lane >> 4, r16 = lane & 15;

  // phase 0: stage q = query + query_pos as bf16
  {
    int fidx = tid * 8;
    int row = fidx >> 8, col = fidx & 255;
    long base = ((long)(b * NQq + q0 + row)) * 256 + col;
    float4 a0 = *(const float4*)(query + base);
    float4 a1 = *(const float4*)(query + base + 4);
    float4 p0 = *(const float4*)(query_pos + base);
    float4 p1 = *(const float4*)(query_pos + base + 4);
    float fv[8] = {a0.x + p0.x, a0.y + p0.y, a0.z + p0.z, a0.w + p0.w,
                   a1.x + p1.x, a1.y + p1.y, a1.z + p1.z, a1.w + p1.w};
    *(uint4*)&sQ[row][col] = pack8(fv);
  }
  __syncthreads();

  // phase 1: C[16][768] = q @ concat(W_off, W_attn)   (48 n-tiles / 8 waves)
  f32x4 acc[6] = {};
  for (int s = 0; s < 8; ++s) {
    bf16x8 af = *(const bf16x8*)&sQ[r16][s * 32 + quad * 8];
#pragma unroll
    for (int t6 = 0; t6 < 6; ++t6) {
      int tile = wave * 6 + t6;
      bf16x8 bfg = *(const bf16x8*)(wcat + ((tile * 8 + s) * 64 + lane) * 8);
      acc[t6] = __builtin_amdgcn_mfma_f32_16x16x32_bf16(af, bfg, acc[t6], 0, 0, 0);
    }
  }
  __syncthreads();                       // sQ dead
#pragma unroll
  for (int t6 = 0; t6 < 6; ++t6) {
    int col = (wave * 6 + t6) * 16 + r16;
#pragma unroll
    for (int rr = 0; rr < 4; ++rr)
      sC[quad * 4 + rr][col] = acc[t6][rr];
  }
  __syncthreads();

  // phase 2: softmax per (m, h) over 32 logits; thread = (m, h, g), g owns 8
  {
    const int m = tid >> 5, hh = (tid >> 2) & 7, g = tid & 3;
    float* p = &sC[m][512 + hh * 32 + g * 8];
    const float* ba = b_attn + hh * 32 + g * 8;
    float v[8];
    float mx = -1e30f;
#pragma unroll
    for (int j = 0; j < 8; ++j) { v[j] = p[j] + ba[j]; mx = fmaxf(mx, v[j]); }
    mx = fmaxf(mx, __shfl_xor(mx, 1));
    mx = fmaxf(mx, __shfl_xor(mx, 2));
    float sum = 0.f;
#pragma unroll
    for (int j = 0; j < 8; ++j) { v[j] = __expf(v[j] - mx); sum += v[j]; }
    sum += __shfl_xor(sum, 1);
    sum += __shfl_xor(sum, 2);
    float inv = 1.f / sum;
#pragma unroll
    for (int j = 0; j < 8; ++j) p[j] = v[j] * inv;
  }
  __syncthreads();

  // phase 3: build packed records.
  //   wgt = (w00|w01, w10|w11) bf16 pairs
  //   off = (o00/64 + 128) in bits 0..13  |  (dy/64) << 14   (dy/64 <= 100)
  // o00 byte offset of corner00, x/y clamped to [-1, Wl-1]; x+1 corner = +64B.
  // Invalid corners have weight 0; guard reads land in wcat/wval around v_ws.
  uint2 wrecs[8];
  u32   orecs[8];
  {
    const int s = tid & 255, mh = tid >> 8;
    const int l = (s >> 3) & 3;
    const int WlI[4] = {100, 50, 25, 13};
    const int baseI[4] = {0, 10000, 12500, 13125};
    const int Wl = WlI[l], Hl = WlI[l], base = baseI[l];
    const float WlF = (float)Wl;
    const float box = b_off[2 * s], boy = b_off[2 * s + 1];
#pragma unroll
    for (int mm = 0; mm < 8; ++mm) {
      int m = mh * 8 + mm;
      float w = sC[m][512 + s];
      float ax = sC[m][2 * s], ay = sC[m][2 * s + 1];
      float2 rp = *(const float2*)(refpts + (((long)(b * NQq + q0 + m)) * LL + l) * 2);
      float x = rp.x * WlF + (ax + box) - 0.5f;
      float y = rp.y * WlF + (ay + boy) - 0.5f;
      float fx0 = floorf(x), fy0 = floorf(y);
      int x0 = (int)fx0, y0 = (int)fy0;
      float fx = x - fx0, fy = y - fy0;
      bool xv0 = (x0 >= 0) & (x0 < Wl);
      bool xv1 = (x0 >= -1) & (x0 < Wl - 1);
      bool yv0 = (y0 >= 0) & (y0 < Hl);
      bool yv1 = (y0 >= -1) & (y0 < Hl - 1);
      float w00 = w * (1.f - fx) * (1.f - fy) * (float)(xv0 & yv0);
      float w01 = w * fx * (1.f - fy) * (float)(xv1 & yv0);
      float w10 = w * (1.f - fx) * fy * (float)(xv0 & yv1);
      float w11 = w * fx * fy * (float)(xv1 & yv1);
      int x0a = min(max(x0, -1), Wl - 1);
      int y0a = min(max(y0, -1), Hl - 1);
      int y1c = min(max(y0 + 1, 0), Hl - 1);
      int o00u = base + y0a * Wl + x0a;              // units of 64B, in [-101, 13293]
      u32 dyu  = (u32)((y1c - y0a) * Wl);            // units of 64B, 0..100
      wrecs[mm].x = bf16_of(w00) | (bf16_of(w01) << 16);
      wrecs[mm].y = bf16_of(w10) | (bf16_of(w11) << 16);
      orecs[mm]   = (u32)(o00u + 128) | (dyu << 14);
    }
  }
  __syncthreads();                       // sC dead
  {
    const int s = tid & 255, mh = tid >> 8;
    const int jsw = (s & 224) | ((s + (s >> 5)) & 31);   // bank swizzle over h
#pragma unroll
    for (int mm = 0; mm < 8; ++mm) {
      sWgt[mh * 8 + mm][jsw] = wrecs[mm];
      sOff[mh * 8 + mm][jsw] = orecs[mm];
    }
  }
  __syncthreads();

  // phase 4: gather — thread = (m:16, h:8, c4:4); 8 channels via dwordx4.
  // Manual batch-2: 8 corner loads issued into distinct live regs, then
  // sched_barrier(0) forbids sinking them into the FMA block -> MLP >= 8.
  {
    const int c4 = tid & 3, hh = (tid >> 2) & 7, m = tid >> 5;
    const u32 vbm = (u32)VWS_OFF + (u32)(b * 8 + hh) * (u32)(LENV * 64)
                  + (u32)c4 * 16u - 8192u;           // folds the +128 bias
    float oacc[8] = {};
#pragma unroll
    for (int i = 0; i < 32; i += 2) {
      const int sr0 = (hh << 5) | ((i + hh) & 31);
      const int sr1 = (hh << 5) | ((i + 1 + hh) & 31);
      uint2 wr0 = sWgt[m][sr0];
      uint2 wr1 = sWgt[m][sr1];
      u32 po0 = sOff[m][sr0];
      u32 po1 = sOff[m][sr1];
      u32 oa0 = vbm + ((po0 & 0x3FFFu) << 6);
      u32 oa1 = oa0 + ((po0 >> 14) << 6);
      u32 ob0 = vbm + ((po1 & 0x3FFFu) << 6);
      u32 ob1 = ob0 + ((po1 >> 14) << 6);
      uint4 qa00 = *(const uint4*)(wsb + oa0);
      uint4 qa01 = *(const uint4*)(wsb + oa0 + 64);
      uint4 qa10 = *(const uint4*)(wsb + oa1);
      uint4 qa11 = *(const uint4*)(wsb + oa1 + 64);
      uint4 qb00 = *(const uint4*)(wsb + ob0);
      uint4 qb01 = *(const uint4*)(wsb + ob0 + 64);
      uint4 qb10 = *(const uint4*)(wsb + ob1);
      uint4 qb11 = *(const uint4*)(wsb + ob1 + 64);
      __builtin_amdgcn_sched_barrier(0);
      acc8(oacc, qa00, blo(wr0.x));
      acc8(oacc, qa01, bhi(wr0.x));
      acc8(oacc, qa10, blo(wr0.y));
      acc8(oacc, qa11, bhi(wr0.y));
      acc8(oacc, qb00, blo(wr1.x));
      acc8(oacc, qb01, bhi(wr1.x));
      acc8(oacc, qb10, blo(wr1.y));
      acc8(oacc, qb11, bhi(wr1.y));
    }
    __syncthreads();                     // tables dead
    *(uint4*)&sO[m][hh * 32 + c4 * 8] = pack8(oacc);
  }
  __syncthreads();

  // phase 5: out = gathered @ W_out + b_out  (16 n-tiles / 8 waves)
  f32x4 acc2[2] = {};
  for (int s = 0; s < 8; ++s) {
    bf16x8 af = *(const bf16x8*)&sO[r16][s * 32 + quad * 8];
#pragma unroll
    for (int t2 = 0; t2 < 2; ++t2) {
      int tile = wave * 2 + t2;
      bf16x8 bfg = *(const bf16x8*)(wout + ((tile * 8 + s) * 64 + lane) * 8);
      acc2[t2] = __builtin_amdgcn_mfma_f32_16x16x32_bf16(af, bfg, acc2[t2], 0, 0, 0);
    }
  }
#pragma unroll
  for (int t2 = 0; t2 < 2; ++t2) {
    int col = (wave * 2 + t2) * 16 + r16;
    float bias = b_out[col];
#pragma unroll
    for (int rr = 0; rr < 4; ++rr) {
      int row = quad * 4 + rr;
      out[((long)(b * NQq + q0 + row)) * 256 + col] = acc2[t2][rr] + bias;
    }
  }
}

extern "C" void kernel_launch(void* const* d_in, const int* in_sizes, int n_in,
                              void* d_out, int out_size, void* d_ws, size_t ws_size,
                              hipStream_t stream) {
  const float* query     = (const float*)d_in[0];
  const float* value     = (const float*)d_in[1];
  const float* query_pos = (const float*)d_in[2];
  const float* refpts    = (const float*)d_in[3];
  const float* W_off     = (const float*)d_in[5];
  const float* b_off     = (const float*)d_in[6];
  const float* W_attn    = (const float*)d_in[7];
  const float* b_attn    = (const float*)d_in[8];
  const float* W_val     = (const float*)d_in[9];
  const float* b_val     = (const float*)d_in[10];
  const float* W_out     = (const float*)d_in[11];
  const float* b_out     = (const float*)d_in[12];
  float* out = (float*)d_out;

  char* ws = (char*)d_ws;
  u16* wcat = (u16*)ws;                                   //    393,216 B @ 0
  u16* v_ws = (u16*)(ws + VWS_OFF);                       // 13,613,056 B
  u16* wval = (u16*)(ws + VWS_OFF + 13613056);            //    131,072 B
  u16* wout = (u16*)(ws + VWS_OFF + 13613056 + 131072);   //    131,072 B

  k_prep<<<dim3(80 * 8), dim3(64), 0, stream>>>(W_off, W_attn, W_val, W_out,
                                                wcat, wval, wout);
  k_valproj<<<dim3((ROWS_V + 63) / 64), dim3(512), 0, stream>>>(value, b_val, wval, v_ws);
  k_attn<<<dim3(BSB * NQq / MQ), dim3(512), 0, stream>>>(
      query, query_pos, refpts, b_off, b_attn, b_out, wcat, wout, ws, out);
}